// Round 1
// baseline (31.526 us; speedup 1.0000x reference)
//
#include <hip/hip_runtime.h>

// Fused Quanvolution + conv + FC + log_softmax for MI355X (gfx950).
//
// Quantum features computed in closed form (Heisenberg-picture derivation):
//   z0 = cos(x00); z1 = cos(x01); z2 = cos(x00)*cos(x10)
//   z3 = 0.5*((c1*c3 - s3) - c0*c2*(c1*c3 + s3))
//
// Layout decisions:
//  - 1 wave = 4 consecutive images; lane = patch id (+64 per step).
//    Each weight read is amortized over 4 images (cuts LDS weight traffic 4x).
//  - fc_w staged in LDS as bf16, gathered layout [o=10][patch=196][feat=8]
//    (feat order: conv ch0..3, z0..3) -> one stride-1 ds_read_b128 per (o,patch).
//    31.4 KB LDS, 2 blocks/CU.
//  - bf16 weight rounding error ~1e-3 on logits << 0.12 threshold.

__global__ __launch_bounds__(256, 2) void quanv_fused(
    const float* __restrict__ x,       // [B][784]
    const float* __restrict__ conv_w,  // [4][1][2][2]
    const float* __restrict__ conv_b,  // [4]
    const float* __restrict__ fc_w,    // [10][1568]
    const float* __restrict__ fc_b,    // [10]
    float* __restrict__ out,           // [B][10]
    int B)
{
    __shared__ unsigned short wlds[15680]; // [o][p][f] bf16

    const int tid = threadIdx.x;

    // ---- stage fc_w into LDS (bf16 RNE, gathered layout) ----
    for (int idx = tid; idx < 15680; idx += 256) {
        int o = idx / 1568;
        int r = idx - o * 1568;
        int p = r >> 3;
        int f = r & 7;
        int j = (f < 4) ? (f * 196 + p) : (784 + p * 4 + (f - 4));
        unsigned int u = __float_as_uint(fc_w[o * 1568 + j]);
        unsigned int h = (u + 0x7FFFu + ((u >> 16) & 1u)) >> 16;
        wlds[idx] = (unsigned short)h;
    }
    __syncthreads();

    const int lane = tid & 63;
    const int wid  = tid >> 6;
    const int b0   = (blockIdx.x * 4 + wid) * 4;  // first image of this wave
    if (b0 >= B) return;

    // uniform small tensors -> (scalar) registers
    float cw[16];
#pragma unroll
    for (int i = 0; i < 16; ++i) cw[i] = conv_w[i];
    float cb[4];
#pragma unroll
    for (int i = 0; i < 4; ++i) cb[i] = conv_b[i];

    float acc[4][10];
#pragma unroll
    for (int m = 0; m < 4; ++m)
#pragma unroll
        for (int o = 0; o < 10; ++o) acc[m][o] = 0.f;

    const float* xb = x + (size_t)b0 * 784;

#pragma unroll
    for (int k = 0; k < 4; ++k) {
        const int p = lane + (k << 6);
        if (p < 196) {
            const int pi  = p / 14;
            const int pj  = p - pi * 14;
            const int off = pi * 56 + pj * 2;   // (2i)*28 + 2j

            float feat[4][8];
#pragma unroll
            for (int m = 0; m < 4; ++m) {
                const float* xp = xb + m * 784 + off;
                const float2 r0 = *reinterpret_cast<const float2*>(xp);
                const float2 r1 = *reinterpret_cast<const float2*>(xp + 28);
                const float x00 = r0.x, x01 = r0.y, x10 = r1.x, x11 = r1.y;
#pragma unroll
                for (int ch = 0; ch < 4; ++ch) {
                    feat[m][ch] = fmaf(x00, cw[ch * 4 + 0],
                                  fmaf(x01, cw[ch * 4 + 1],
                                  fmaf(x10, cw[ch * 4 + 2],
                                  fmaf(x11, cw[ch * 4 + 3], cb[ch]))));
                }
                const float c0 = __cosf(x00);
                const float c1 = __cosf(x01);
                const float c2 = __cosf(x10);
                float s3, c3;
                __sincosf(x11, &s3, &c3);
                const float t = c0 * c2;       // z2
                const float u = c1 * c3;
                feat[m][4] = c0;
                feat[m][5] = c1;
                feat[m][6] = t;
                feat[m][7] = 0.5f * ((u - s3) - t * (u + s3));
            }

            // FC accumulate: one b128 LDS read per output o serves 4 images
#pragma unroll
            for (int o = 0; o < 10; ++o) {
                const uint4 d = *reinterpret_cast<const uint4*>(&wlds[o * 1568 + p * 8]);
                float w[8];
                w[0] = __uint_as_float(d.x << 16);
                w[1] = __uint_as_float(d.x & 0xFFFF0000u);
                w[2] = __uint_as_float(d.y << 16);
                w[3] = __uint_as_float(d.y & 0xFFFF0000u);
                w[4] = __uint_as_float(d.z << 16);
                w[5] = __uint_as_float(d.z & 0xFFFF0000u);
                w[6] = __uint_as_float(d.w << 16);
                w[7] = __uint_as_float(d.w & 0xFFFF0000u);
#pragma unroll
                for (int m = 0; m < 4; ++m) {
                    float a = acc[m][o];
#pragma unroll
                    for (int f = 0; f < 8; ++f) a = fmaf(feat[m][f], w[f], a);
                    acc[m][o] = a;
                }
            }
        }
    }

    // ---- wave butterfly reduce (40 scalars over 64 lanes) ----
#pragma unroll
    for (int m = 0; m < 4; ++m)
#pragma unroll
        for (int o = 0; o < 10; ++o) {
            float v = acc[m][o];
            v += __shfl_xor(v, 32);
            v += __shfl_xor(v, 16);
            v += __shfl_xor(v, 8);
            v += __shfl_xor(v, 4);
            v += __shfl_xor(v, 2);
            v += __shfl_xor(v, 1);
            acc[m][o] = v;
        }

    // ---- log_softmax + store: lane m handles image b0+m ----
    if (lane < 4) {
        const int m = lane;
        float lg[10];
#pragma unroll
        for (int o = 0; o < 10; ++o) lg[o] = acc[m][o] + fc_b[o];
        float mx = lg[0];
#pragma unroll
        for (int o = 1; o < 10; ++o) mx = fmaxf(mx, lg[o]);
        float se = 0.f;
#pragma unroll
        for (int o = 0; o < 10; ++o) se += __expf(lg[o] - mx);
        const float lse = __logf(se) + mx;
        float* op = out + (size_t)(b0 + m) * 10;
#pragma unroll
        for (int o = 0; o < 10; ++o) op[o] = lg[o] - lse;
    }
}

extern "C" void kernel_launch(void* const* d_in, const int* in_sizes, int n_in,
                              void* d_out, int out_size, void* d_ws, size_t ws_size,
                              hipStream_t stream) {
    const float* x      = (const float*)d_in[0];
    const float* conv_w = (const float*)d_in[1];
    const float* conv_b = (const float*)d_in[2];
    const float* fc_w   = (const float*)d_in[3];
    const float* fc_b   = (const float*)d_in[4];
    float* out = (float*)d_out;

    const int B = in_sizes[0] / 784;          // 8192
    const int blocks = (B + 15) / 16;         // 16 images per 256-thread block
    quanv_fused<<<blocks, 256, 0, stream>>>(x, conv_w, conv_b, fc_w, fc_b, out, B);
}

// Round 3
// 30.046 us; speedup vs baseline: 1.0493x; 1.0493x over previous
//
#include <hip/hip_runtime.h>

// Fused Quanvolution + conv + FC + log_softmax for MI355X (gfx950).
//
// Quantum features in closed form (Heisenberg-picture derivation, verified R1):
//   z0 = cos(x00); z1 = cos(x01); z2 = cos(x00)*cos(x10)
//   z3 = 0.5*((c1*c3 - s3) - c0*c2*(c1*c3 + s3))
//
// R3 = R2 with the type fix: cvt_pkrtz returns __fp16 ext_vector(2); use that
// type throughout (half2v, LDS element type).
//
// R2 changes vs R1 (31.5 us):
//  - FC via v_dot2_f32_f16 (__builtin_amdgcn_fdot2): f16 weight pairs in LDS,
//    features packed with v_cvt_pkrtz -> 2 MACs/inst, no bf16 unpack ALU.
//  - 2 images per lane (was 4): acc[2][10]+feat halve VGPR footprint; grid
//    1024 blocks -> 4 blocks/CU co-resident (LDS 31.4KB caps at 5), 16 waves/CU.
//  - fc_w staged with coalesced float4 loads, scatter moved to LDS-write side.

typedef __fp16 half2v __attribute__((ext_vector_type(2)));

__global__ __launch_bounds__(256, 4) void quanv_fused(
    const float* __restrict__ x,       // [B][784]
    const float* __restrict__ conv_w,  // [4][1][2][2]
    const float* __restrict__ conv_b,  // [4]
    const float* __restrict__ fc_w,    // [10][1568]
    const float* __restrict__ fc_b,    // [10]
    float* __restrict__ out,           // [B][10]
    int B)
{
    __shared__ __fp16 wlds[15680]; // [o=10][p=196][f=8] f16

    const int tid = threadIdx.x;

    // ---- stage fc_w into LDS: coalesced float4 reads, scattered f16 writes ----
    for (int base = tid * 4; base < 15680; base += 1024) {
        const float4 v = *reinterpret_cast<const float4*>(&fc_w[base]);
        const float el[4] = {v.x, v.y, v.z, v.w};
#pragma unroll
        for (int e = 0; e < 4; ++e) {
            const int j = base + e;
            const int o = j / 1568;
            const int r = j - o * 1568;
            int p, f;
            if (r < 784) { f = r / 196; p = r - f * 196; }
            else         { const int r2 = r - 784; p = r2 >> 2; f = 4 + (r2 & 3); }
            wlds[o * 1568 + p * 8 + f] = (__fp16)el[e];
        }
    }
    __syncthreads();

    const int lane = tid & 63;
    const int wid  = tid >> 6;
    const int b0   = (blockIdx.x * 4 + wid) * 2;  // first of 2 images for this wave
    if (b0 >= B) return;

    float cw[16];
#pragma unroll
    for (int i = 0; i < 16; ++i) cw[i] = conv_w[i];
    float cb[4];
#pragma unroll
    for (int i = 0; i < 4; ++i) cb[i] = conv_b[i];

    float acc[2][10];
#pragma unroll
    for (int m = 0; m < 2; ++m)
#pragma unroll
        for (int o = 0; o < 10; ++o) acc[m][o] = 0.f;

    const float* xb = x + (size_t)b0 * 784;

#pragma unroll
    for (int k = 0; k < 4; ++k) {
        const int p = lane + (k << 6);
        if (p < 196) {
            const int pi  = p / 14;
            const int pj  = p - pi * 14;
            const int off = pi * 56 + pj * 2;   // (2i)*28 + 2j floats

            half2v fm[2][4];
#pragma unroll
            for (int m = 0; m < 2; ++m) {
                const float* xp = xb + m * 784 + off;
                const float2 r0 = *reinterpret_cast<const float2*>(xp);
                const float2 r1 = *reinterpret_cast<const float2*>(xp + 28);
                const float x00 = r0.x, x01 = r0.y, x10 = r1.x, x11 = r1.y;
                float ft[4];
#pragma unroll
                for (int ch = 0; ch < 4; ++ch) {
                    ft[ch] = fmaf(x00, cw[ch * 4 + 0],
                             fmaf(x01, cw[ch * 4 + 1],
                             fmaf(x10, cw[ch * 4 + 2],
                             fmaf(x11, cw[ch * 4 + 3], cb[ch]))));
                }
                const float c0 = __cosf(x00);
                const float c1 = __cosf(x01);
                const float c2 = __cosf(x10);
                float s3, c3;
                __sincosf(x11, &s3, &c3);
                const float t = c0 * c2;            // z2
                const float u = c1 * c3;
                const float z3 = 0.5f * ((u - s3) - t * (u + s3));
                fm[m][0] = __builtin_amdgcn_cvt_pkrtz(ft[0], ft[1]);
                fm[m][1] = __builtin_amdgcn_cvt_pkrtz(ft[2], ft[3]);
                fm[m][2] = __builtin_amdgcn_cvt_pkrtz(c0, c1);
                fm[m][3] = __builtin_amdgcn_cvt_pkrtz(t, z3);
            }

            // FC accumulate: one b128 LDS read per output o serves both images,
            // 4x v_dot2_f32_f16 per (o, image).
#pragma unroll
            for (int o = 0; o < 10; ++o) {
                const uint4 d = *reinterpret_cast<const uint4*>(&wlds[o * 1568 + p * 8]);
                const half2v w0 = __builtin_bit_cast(half2v, d.x);
                const half2v w1 = __builtin_bit_cast(half2v, d.y);
                const half2v w2 = __builtin_bit_cast(half2v, d.z);
                const half2v w3 = __builtin_bit_cast(half2v, d.w);
#pragma unroll
                for (int m = 0; m < 2; ++m) {
                    float a = acc[m][o];
                    a = __builtin_amdgcn_fdot2(fm[m][0], w0, a, false);
                    a = __builtin_amdgcn_fdot2(fm[m][1], w1, a, false);
                    a = __builtin_amdgcn_fdot2(fm[m][2], w2, a, false);
                    a = __builtin_amdgcn_fdot2(fm[m][3], w3, a, false);
                    acc[m][o] = a;
                }
            }
        }
    }

    // ---- wave butterfly reduce (20 scalars over 64 lanes) ----
#pragma unroll
    for (int m = 0; m < 2; ++m)
#pragma unroll
        for (int o = 0; o < 10; ++o) {
            float v = acc[m][o];
            v += __shfl_xor(v, 32);
            v += __shfl_xor(v, 16);
            v += __shfl_xor(v, 8);
            v += __shfl_xor(v, 4);
            v += __shfl_xor(v, 2);
            v += __shfl_xor(v, 1);
            acc[m][o] = v;
        }

    // ---- log_softmax + store: lane m (m<2) handles image b0+m ----
    if (lane < 2) {
        const int m = lane;
        float lg[10];
#pragma unroll
        for (int o = 0; o < 10; ++o) lg[o] = acc[m][o] + fc_b[o];
        float mx = lg[0];
#pragma unroll
        for (int o = 1; o < 10; ++o) mx = fmaxf(mx, lg[o]);
        float se = 0.f;
#pragma unroll
        for (int o = 0; o < 10; ++o) se += __expf(lg[o] - mx);
        const float lse = __logf(se) + mx;
        float* op = out + (size_t)(b0 + m) * 10;
#pragma unroll
        for (int o = 0; o < 10; ++o) op[o] = lg[o] - lse;
    }
}

extern "C" void kernel_launch(void* const* d_in, const int* in_sizes, int n_in,
                              void* d_out, int out_size, void* d_ws, size_t ws_size,
                              hipStream_t stream) {
    const float* x      = (const float*)d_in[0];
    const float* conv_w = (const float*)d_in[1];
    const float* conv_b = (const float*)d_in[2];
    const float* fc_w   = (const float*)d_in[3];
    const float* fc_b   = (const float*)d_in[4];
    float* out = (float*)d_out;

    const int B = in_sizes[0] / 784;          // 8192
    const int blocks = (B + 7) / 8;           // 8 images per 256-thread block
    quanv_fused<<<blocks, 256, 0, stream>>>(x, conv_w, conv_b, fc_w, fc_b, out, B);
}

// Round 4
// 20.661 us; speedup vs baseline: 1.5259x; 1.4542x over previous
//
#include <hip/hip_runtime.h>

// Fused Quanvolution + conv + FC + log_softmax via MFMA, MI355X (gfx950).
//
// Quantum features in closed form (Heisenberg-picture, verified R1-R3):
//   z0 = cos(x00); z1 = cos(x01); z2 = cos(x00)*cos(x10)
//   z3 = 0.5*((c1*c3 - s3) - c0*c2*(c1*c3 + s3))
//
// R4: FC as mfma_f32_16x16x32_f16. Reordered K = [patch][8 feats]; the same
// reorder is applied to A (features) and B (weights) so the contraction is
// invariant. Lane l of each wave: img = l&15 (A row), patch-slot = l>>4
// (k-slice), o = l&15 (B col). One MFMA per 4-patch group. No LDS weights,
// no staging barrier, no butterfly reduce, no k-unroll register blowup.
// Block: 512 thr = 8 waves, owns 16 images; waves split the 49 patch-groups
// contiguously (6 or 7 each). Grid 512 blocks -> 4096 waves.

typedef _Float16 f16x8 __attribute__((ext_vector_type(8)));
typedef float    f32x4 __attribute__((ext_vector_type(4)));

__global__ __launch_bounds__(512, 4) void quanv_mfma(
    const float* __restrict__ x,       // [B][784]
    const float* __restrict__ conv_w,  // [4][1][2][2]
    const float* __restrict__ conv_b,  // [4]
    const float* __restrict__ fc_w,    // [10][1568]
    const float* __restrict__ fc_b,    // [10]
    float* __restrict__ out,           // [B][10]
    int B)
{
    __shared__ float red[8][16][16];   // per-wave partial C tiles

    const int tid  = threadIdx.x;
    const int wid  = tid >> 6;
    const int lane = tid & 63;
    const int l15  = lane & 15;        // A row (img) AND B col (o)
    const int slot = lane >> 4;        // k-slice = patch within 4-patch group
    const int b0   = blockIdx.x * 16;

    // uniform small tensors
    float cw[16], cb[4];
#pragma unroll
    for (int i = 0; i < 16; ++i) cw[i] = conv_w[i];
#pragma unroll
    for (int i = 0; i < 4; ++i) cb[i] = conv_b[i];

    // B-operand setup: o = l15, classes 10..15 masked to zero
    const int   o   = l15;
    const int   oc  = (o < 10) ? o : 9;
    const float msk = (o < 10) ? 1.f : 0.f;
    const float* wr = fc_w + oc * 1568;

    // A-operand setup: img = b0 + l15 (clamp for safety; grid sized exactly)
    int img = b0 + l15;
    if (img >= B) img = B - 1;
    const float* xi = x + (size_t)img * 784;

    f32x4 acc = {0.f, 0.f, 0.f, 0.f};

    // contiguous patch-group range for this wave (49 groups over 8 waves)
    const int g0 = (wid * 49) >> 3;
    const int g1 = ((wid + 1) * 49) >> 3;

    for (int g = g0; g < g1; ++g) {
        const int p   = (g << 2) + slot;       // patch id, < 196
        const int pi  = p / 14;
        const int pj  = p - pi * 14;
        const int off = pi * 56 + pj * 2;      // float offset of patch corner

        // ---- A fragment: 8 features of (img, p) ----
        const float2 r0 = *reinterpret_cast<const float2*>(xi + off);
        const float2 r1 = *reinterpret_cast<const float2*>(xi + off + 28);
        const float x00 = r0.x, x01 = r0.y, x10 = r1.x, x11 = r1.y;

        const float ft0 = fmaf(x00, cw[0],  fmaf(x01, cw[1],  fmaf(x10, cw[2],  fmaf(x11, cw[3],  cb[0]))));
        const float ft1 = fmaf(x00, cw[4],  fmaf(x01, cw[5],  fmaf(x10, cw[6],  fmaf(x11, cw[7],  cb[1]))));
        const float ft2 = fmaf(x00, cw[8],  fmaf(x01, cw[9],  fmaf(x10, cw[10], fmaf(x11, cw[11], cb[2]))));
        const float ft3 = fmaf(x00, cw[12], fmaf(x01, cw[13], fmaf(x10, cw[14], fmaf(x11, cw[15], cb[3]))));

        const float c0 = __cosf(x00);
        const float c1 = __cosf(x01);
        const float c2 = __cosf(x10);
        const float s3 = __sinf(x11);
        const float c3 = __cosf(x11);
        const float t  = c0 * c2;              // z2
        const float u  = c1 * c3;
        const float z3 = 0.5f * ((u - s3) - t * (u + s3));

        f16x8 a;
        a[0] = (_Float16)ft0; a[1] = (_Float16)ft1;
        a[2] = (_Float16)ft2; a[3] = (_Float16)ft3;
        a[4] = (_Float16)c0;  a[5] = (_Float16)c1;
        a[6] = (_Float16)t;   a[7] = (_Float16)z3;

        // ---- B fragment: 8 weights of (p, o), same feature order ----
        const float  w0 = wr[p]       * msk;
        const float  w1 = wr[196 + p] * msk;
        const float  w2 = wr[392 + p] * msk;
        const float  w3 = wr[588 + p] * msk;
        const float4 wq = *reinterpret_cast<const float4*>(wr + 784 + p * 4);

        f16x8 b;
        b[0] = (_Float16)w0;          b[1] = (_Float16)w1;
        b[2] = (_Float16)w2;          b[3] = (_Float16)w3;
        b[4] = (_Float16)(wq.x * msk); b[5] = (_Float16)(wq.y * msk);
        b[6] = (_Float16)(wq.z * msk); b[7] = (_Float16)(wq.w * msk);

        acc = __builtin_amdgcn_mfma_f32_16x16x32_f16(a, b, acc, 0, 0, 0);
    }

    // ---- partial C -> LDS: lane holds C[row=(slot*4+r)][col=l15] = [img][o]
#pragma unroll
    for (int r = 0; r < 4; ++r)
        red[wid][slot * 4 + r][l15] = acc[r];
    __syncthreads();

    // ---- sum the 8 wave-partials: thread t owns cell (row=t>>4, col=t&15)
    if (tid < 256) {
        const int row = tid >> 4, col = tid & 15;
        float s = 0.f;
#pragma unroll
        for (int w = 0; w < 8; ++w) s += red[w][row][col];
        red[0][row][col] = s;   // in-place: each cell read/written by one thread
    }
    __syncthreads();

    // ---- log_softmax + store: lane im handles image b0+im ----
    if (tid < 16) {
        const int im = tid;
        if (b0 + im < B) {
            float lg[10];
#pragma unroll
            for (int j = 0; j < 10; ++j) lg[j] = red[0][im][j] + fc_b[j];
            float mx = lg[0];
#pragma unroll
            for (int j = 1; j < 10; ++j) mx = fmaxf(mx, lg[j]);
            float se = 0.f;
#pragma unroll
            for (int j = 0; j < 10; ++j) se += __expf(lg[j] - mx);
            const float lse = __logf(se) + mx;
            float* op = out + (size_t)(b0 + im) * 10;
#pragma unroll
            for (int j = 0; j < 10; ++j) op[j] = lg[j] - lse;
        }
    }
}

extern "C" void kernel_launch(void* const* d_in, const int* in_sizes, int n_in,
                              void* d_out, int out_size, void* d_ws, size_t ws_size,
                              hipStream_t stream) {
    const float* x      = (const float*)d_in[0];
    const float* conv_w = (const float*)d_in[1];
    const float* conv_b = (const float*)d_in[2];
    const float* fc_w   = (const float*)d_in[3];
    const float* fc_b   = (const float*)d_in[4];
    float* out = (float*)d_out;

    const int B = in_sizes[0] / 784;           // 8192
    const int blocks = (B + 15) / 16;          // 16 images per block
    quanv_mfma<<<blocks, 512, 0, stream>>>(x, conv_w, conv_b, fc_w, fc_b, out, B);
}